// Round 3
// baseline (287.282 us; speedup 1.0000x reference)
//
#include <hip/hip_runtime.h>
#include <hip/hip_bf16.h>

#define CIN 128
#define COUT 512
#define NEG_SLOPE 0.1f

typedef __bf16 bf16x8 __attribute__((ext_vector_type(8)));
typedef float f32x4 __attribute__((ext_vector_type(4)));

static __device__ __forceinline__ unsigned short f2bf(float f) {
  unsigned int u = __builtin_bit_cast(unsigned int, f);
  unsigned int lsb = (u >> 16) & 1u;
  u += 0x7fffu + lsb;  // round-to-nearest-even
  return (unsigned short)(u >> 16);
}
static __device__ __forceinline__ float bf_lo(unsigned int u) {
  return __builtin_bit_cast(float, u << 16);
}
static __device__ __forceinline__ float bf_hi(unsigned int u) {
  return __builtin_bit_cast(float, u & 0xffff0000u);
}
static __device__ __forceinline__ unsigned int pack2(float lo, float hi) {
  return (unsigned int)f2bf(lo) | ((unsigned int)f2bf(hi) << 16);
}

// ---- Edge dtype probe: int64 stored data has every odd int32 word == 0 ----
__global__ void detect_kernel(const int* __restrict__ raw, int* __restrict__ flag, int E) {
  __shared__ int any_nonzero;
  int tid = threadIdx.x;  // 64 threads
  if (tid == 0) any_nonzero = 0;
  __syncthreads();
  int v1 = raw[2 * tid + 1];
  int v2 = raw[2 * (E / 2) + 2 * tid + 1];
  if (v1 != 0 || v2 != 0) atomicOr(&any_nonzero, 1);
  __syncthreads();
  if (tid == 0) *flag = any_nonzero ? 0 : 1;  // 1 => data is int64
}

// Fused decode + degree count + per-edge rank (atomicAdd's return value is
// the edge's slot within its destination row -> scatter needs no atomics).
__global__ void decode_count_kernel(const int* __restrict__ raw, const int* __restrict__ flag,
                                    int* __restrict__ srcA, int* __restrict__ dstA,
                                    int* __restrict__ rank, int* __restrict__ cnt,
                                    int E, int N) {
  int e = blockIdx.x * blockDim.x + threadIdx.x;
  if (e >= E) return;
  int is64 = *flag;
  int s, d;
  if (is64) {
    int2 sv = ((const int2*)raw)[e];       // 8B vector load, low word = value
    int2 dv = ((const int2*)raw)[E + e];
    s = sv.x;
    d = dv.x;
  } else {
    s = raw[e];
    d = raw[E + e];
  }
  if ((unsigned)s >= (unsigned)N) s = 0;
  if ((unsigned)d >= (unsigned)N) d = 0;
  srcA[e] = s;
  dstA[e] = d;
  rank[e] = atomicAdd(&cnt[d], 1);
}

// Merged prep: xscale (first N*32 groups) + W->bf16 conversion (next 16384
// groups). One dispatch instead of two (removes a serial launch gap).
__global__ __launch_bounds__(256) void prep_kernel(const float* __restrict__ x,
                                                   const int* __restrict__ cnt,
                                                   unsigned short* __restrict__ xs,
                                                   const float* __restrict__ W,
                                                   unsigned short* __restrict__ Wbf, int N) {
  int idx = blockIdx.x * blockDim.x + threadIdx.x;  // one float4 group
  int nx = N * (CIN / 4);
  if (idx < nx) {
    int row = idx >> 5;  // 32 float4 groups per row
    float d = 1.0f / sqrtf((float)(cnt[row] + 1));  // +1 = self-loop
    float4 v = ((const float4*)x)[idx];
    ushort4 o;
    o.x = f2bf(v.x * d); o.y = f2bf(v.y * d); o.z = f2bf(v.z * d); o.w = f2bf(v.w * d);
    ((ushort4*)xs)[idx] = o;
  } else {
    int i = idx - nx;
    if (i < (COUT * CIN / 4)) {
      float4 v = ((const float4*)W)[i];
      ushort4 o;
      o.x = f2bf(v.x); o.y = f2bf(v.y); o.z = f2bf(v.z); o.w = f2bf(v.w);
      ((ushort4*)Wbf)[i] = o;
    }
  }
}

// ---- Hierarchical device-wide exclusive scan (2 kernels; block offsets in
// bsum are folded into consumers instead of a 3rd pass) ----
__global__ __launch_bounds__(256) void scan1_kernel(const int* __restrict__ cnt,
                                                    int* __restrict__ rowptr,
                                                    int* __restrict__ bsum, int N) {
  __shared__ int buf[256];
  int tid = threadIdx.x;
  int base = blockIdx.x * 1024 + tid * 4;
  int v[4];
  int tot = 0;
#pragma unroll
  for (int k = 0; k < 4; ++k) {
    int i = base + k;
    v[k] = (i < N) ? cnt[i] : 0;
    tot += v[k];
  }
  buf[tid] = tot;
  __syncthreads();
  for (int off = 1; off < 256; off <<= 1) {
    int t = (tid >= off) ? buf[tid - off] : 0;
    __syncthreads();
    buf[tid] += t;
    __syncthreads();
  }
  int run = buf[tid] - tot;
  if (tid == 255) bsum[blockIdx.x] = buf[255];
#pragma unroll
  for (int k = 0; k < 4; ++k) {
    int i = base + k;
    if (i < N) rowptr[i] = run;
    run += v[k];
  }
}

__global__ void scan2_kernel(int* __restrict__ bsum, int nb) {
  __shared__ int buf[256];
  int tid = threadIdx.x;
  int v = (tid < nb) ? bsum[tid] : 0;
  buf[tid] = v;
  __syncthreads();
  for (int off = 1; off < 256; off <<= 1) {
    int t = (tid >= off) ? buf[tid - off] : 0;
    __syncthreads();
    buf[tid] += t;
    __syncthreads();
  }
  if (tid < nb) bsum[tid] = buf[tid] - v;
}

// Atomic-free scatter: slot precomputed in decode (rank); block offset from
// bsum folded in here (scan3 eliminated).
__global__ void scatter_kernel(const int* __restrict__ srcA, const int* __restrict__ dstA,
                               const int* __restrict__ rank, const int* __restrict__ rowptr,
                               const int* __restrict__ bsum, int* __restrict__ col, int E) {
  int e = blockIdx.x * blockDim.x + threadIdx.x;
  if (e < E) {
    int d = dstA[e];
    col[rowptr[d] + bsum[d >> 10] + rank[e]] = srcA[e];
  }
}

// Gather hop over pre-scaled bf16 rows (256 B/row).
// ONE NODE PER WAVE: lane = (grp 0..3, sub 0..15). Each step the wave pulls 4
// neighbor rows (grp picks the row, sub picks the 16B chunk), so trip count is
// wave-uniform -> no intra-wave degree divergence. Cross-grp reduce via 2x
// shfl_xor. Output: SQ ? di^2 * sum (h1s) : di * sum (h2, feeds GEMM).
template <bool SQ>
__global__ __launch_bounds__(256) void hop_kernel(
    const unsigned short* __restrict__ Xs,
    const int* __restrict__ rowptr, const int* __restrict__ cnt,
    const int* __restrict__ bsum,
    const int* __restrict__ col, unsigned short* __restrict__ Y, int N) {
  int lane = threadIdx.x & 63;
  int wid = threadIdx.x >> 6;
  int node = blockIdx.x * 4 + wid;
  if (node >= N) return;
  int sub = lane & 15;
  int grp = lane >> 4;
  int beg = rowptr[node] + bsum[node >> 10];
  int num = cnt[node];
  const uint4* X4 = (const uint4*)Xs;  // one row = 16 uint4
  float acc[8] = {0.f, 0.f, 0.f, 0.f, 0.f, 0.f, 0.f, 0.f};
  if (grp == 0) {  // self-loop term
    uint4 s = X4[(size_t)node * 16 + sub];
    acc[0] = bf_lo(s.x); acc[1] = bf_hi(s.x);
    acc[2] = bf_lo(s.y); acc[3] = bf_hi(s.y);
    acc[4] = bf_lo(s.z); acc[5] = bf_hi(s.z);
    acc[6] = bf_lo(s.w); acc[7] = bf_hi(s.w);
  }
  const int* cp = col + beg;
  int kb = 0;
  // main: 16 rows per step (4 per grp) -> 4 outstanding row loads per lane
  for (; kb + 16 <= num; kb += 16) {
    int j0 = cp[kb + grp];
    int j1 = cp[kb + 4 + grp];
    int j2 = cp[kb + 8 + grp];
    int j3 = cp[kb + 12 + grp];
    uint4 v0 = X4[(size_t)j0 * 16 + sub];
    uint4 v1 = X4[(size_t)j1 * 16 + sub];
    uint4 v2 = X4[(size_t)j2 * 16 + sub];
    uint4 v3 = X4[(size_t)j3 * 16 + sub];
    acc[0] += bf_lo(v0.x); acc[1] += bf_hi(v0.x);
    acc[2] += bf_lo(v0.y); acc[3] += bf_hi(v0.y);
    acc[4] += bf_lo(v0.z); acc[5] += bf_hi(v0.z);
    acc[6] += bf_lo(v0.w); acc[7] += bf_hi(v0.w);
    acc[0] += bf_lo(v1.x); acc[1] += bf_hi(v1.x);
    acc[2] += bf_lo(v1.y); acc[3] += bf_hi(v1.y);
    acc[4] += bf_lo(v1.z); acc[5] += bf_hi(v1.z);
    acc[6] += bf_lo(v1.w); acc[7] += bf_hi(v1.w);
    acc[0] += bf_lo(v2.x); acc[1] += bf_hi(v2.x);
    acc[2] += bf_lo(v2.y); acc[3] += bf_hi(v2.y);
    acc[4] += bf_lo(v2.z); acc[5] += bf_hi(v2.z);
    acc[6] += bf_lo(v2.w); acc[7] += bf_hi(v2.w);
    acc[0] += bf_lo(v3.x); acc[1] += bf_hi(v3.x);
    acc[2] += bf_lo(v3.y); acc[3] += bf_hi(v3.y);
    acc[4] += bf_lo(v3.z); acc[5] += bf_hi(v3.z);
    acc[6] += bf_lo(v3.w); acc[7] += bf_hi(v3.w);
  }
  // tail: 4 rows per step, masked by (k < num)
  for (; kb < num; kb += 4) {
    int k = kb + grp;
    if (k < num) {
      int j0 = cp[k];
      uint4 v0 = X4[(size_t)j0 * 16 + sub];
      acc[0] += bf_lo(v0.x); acc[1] += bf_hi(v0.x);
      acc[2] += bf_lo(v0.y); acc[3] += bf_hi(v0.y);
      acc[4] += bf_lo(v0.z); acc[5] += bf_hi(v0.z);
      acc[6] += bf_lo(v0.w); acc[7] += bf_hi(v0.w);
    }
  }
  // reduce across the 4 grps (lane bits 4,5)
#pragma unroll
  for (int r = 0; r < 8; ++r) acc[r] += __shfl_xor(acc[r], 16, 64);
#pragma unroll
  for (int r = 0; r < 8; ++r) acc[r] += __shfl_xor(acc[r], 32, 64);
  if (grp == 0) {
    float di = 1.0f / sqrtf((float)(num + 1));
    float sc = SQ ? di * di : di;
    uint4 o;
    o.x = pack2(acc[0] * sc, acc[1] * sc);
    o.y = pack2(acc[2] * sc, acc[3] * sc);
    o.z = pack2(acc[4] * sc, acc[5] * sc);
    o.w = pack2(acc[6] * sc, acc[7] * sc);
    ((uint4*)Y)[(size_t)node * 16 + sub] = o;
  }
}

// y = h2 @ W^T + b, LeakyReLU. Block = 32 rows x full COUT=512.
// Swapped-operand MFMA (lane&15 = m, quad*4+reg = n) -- layout verified by
// round-2 pass. NEW: epilogue stages each 16-row half-tile in LDS
// (16x516 f32, padded for b128 align + <=2-way write conflicts), then streams
// it out with dense stores: each wave instr writes 64 lanes x 16 B = 1 KB
// CONTIGUOUS. Direct per-lane float4 stores scattered 64 chunks across 64
// 2KB-strided lines per instr, capping the store path at ~2 TB/s (gemm ~55us).
__global__ __launch_bounds__(256) void gemm_kernel(
    const unsigned short* __restrict__ Abf, const unsigned short* __restrict__ Wbf,
    const float* __restrict__ bias, float* __restrict__ out, int M) {
  __shared__ float tile[16 * 516];  // 33 KB
  int wave = threadIdx.x >> 6;
  int lane = threadIdx.x & 63;
  int quad = lane >> 4;
  int l16 = lane & 15;
  int mbase = blockIdx.x * 32;

  int m0 = mbase + l16;
  int m1 = mbase + 16 + l16;
  bool v0 = m0 < M;
  bool v1 = m1 < M;

  // B-operand fragments (h2 rows, K contiguous): lane l16 = col(m), quad = k-chunk
  bf16x8 af[2][4];
#pragma unroll
  for (int kk = 0; kk < 4; ++kk) {
    af[0][kk] = v0 ? *(const bf16x8*)(Abf + (size_t)m0 * CIN + kk * 32 + quad * 8) : bf16x8{};
    af[1][kk] = v1 ? *(const bf16x8*)(Abf + (size_t)m1 * CIN + kk * 32 + quad * 8) : bf16x8{};
  }

  int nbase = wave * 128;
  f32x4 acc0[8], acc1[8];
#pragma unroll
  for (int nt = 0; nt < 8; ++nt) {
    int nrow = nbase + nt * 16 + l16;  // W row this lane loads (A-operand)
    bf16x8 wf[4];
#pragma unroll
    for (int kk = 0; kk < 4; ++kk)
      wf[kk] = *(const bf16x8*)(Wbf + (size_t)nrow * CIN + kk * 32 + quad * 8);
    f32x4 a0 = {}, a1 = {};
#pragma unroll
    for (int kk = 0; kk < 4; ++kk) {
      a0 = __builtin_amdgcn_mfma_f32_16x16x32_bf16(wf[kk], af[0][kk], a0, 0, 0, 0);
      a1 = __builtin_amdgcn_mfma_f32_16x16x32_bf16(wf[kk], af[1][kk], a1, 0, 0, 0);
    }
    acc0[nt] = a0;
    acc1[nt] = a1;
  }

  // ---- epilogue: two 16-row halves through LDS ----
#pragma unroll
  for (int half = 0; half < 2; ++half) {
    if (half) __syncthreads();  // WAR: previous half streamed out
#pragma unroll
    for (int nt = 0; nt < 8; ++nt) {
      int n0 = nbase + nt * 16 + quad * 4;
      float4 bv = *(const float4*)(bias + n0);
      f32x4 a = half ? acc1[nt] : acc0[nt];
      float4 o;
      o.x = a[0] + bv.x; o.x = (o.x >= 0.f) ? o.x : NEG_SLOPE * o.x;
      o.y = a[1] + bv.y; o.y = (o.y >= 0.f) ? o.y : NEG_SLOPE * o.y;
      o.z = a[2] + bv.z; o.z = (o.z >= 0.f) ? o.z : NEG_SLOPE * o.z;
      o.w = a[3] + bv.w; o.w = (o.w >= 0.f) ? o.w : NEG_SLOPE * o.w;
      *(float4*)&tile[l16 * 516 + n0] = o;
    }
    __syncthreads();
    // stream 16 rows x 2048 B: 8 iters x (256 threads x 16 B) = 2 rows/iter,
    // each wave instr = 1 KB contiguous.
#pragma unroll
    for (int it = 0; it < 8; ++it) {
      int r = it * 2 + (threadIdx.x >> 7);
      int c = (threadIdx.x & 127) * 4;
      int m = mbase + half * 16 + r;
      if (m < M) *(float4*)(out + (size_t)m * COUT + c) = *(const float4*)&tile[r * 516 + c];
    }
  }
}

static inline size_t align_up(size_t v, size_t a) { return (v + a - 1) & ~(a - 1); }

extern "C" void kernel_launch(void* const* d_in, const int* in_sizes, int n_in,
                              void* d_out, int out_size, void* d_ws, size_t ws_size,
                              hipStream_t stream) {
  const float* x = (const float*)d_in[0];
  const int* edge_raw = (const int*)d_in[1];
  const float* W = (const float*)d_in[2];
  const float* b = (const float*)d_in[3];
  float* out = (float*)d_out;

  const int N = in_sizes[0] / CIN;
  const int E = in_sizes[1] / 2;
  const int NB = (N + 1023) / 1024;  // scan blocks (49 for N=50000)

  // Workspace layout
  char* w = (char*)d_ws;
  int* flag = (int*)w;            w += align_up(sizeof(int), 256);
  int* bsum = (int*)w;            w += align_up(256 * 4, 256);
  int* cnt = (int*)w;             w += align_up((size_t)N * 4, 256);
  int* rowptr = (int*)w;          w += align_up((size_t)N * 4, 256);
  int* srcA = (int*)w;            w += align_up((size_t)E * 4, 256);
  int* dstA = (int*)w;            w += align_up((size_t)E * 4, 256);
  int* rank = (int*)w;            w += align_up((size_t)E * 4, 256);
  int* col = (int*)w;             w += align_up((size_t)E * 4, 256);
  unsigned short* h2bf = (unsigned short*)w;  w += align_up((size_t)N * CIN * 2, 256);
  unsigned short* Wbf = (unsigned short*)w;   w += align_up((size_t)COUT * CIN * 2, 256);

  // bf16 row buffers in the tail of d_out (scratch until GEMM's final write).
  size_t outb = (size_t)out_size * sizeof(float);
  size_t rowb = (size_t)N * CIN * sizeof(unsigned short);
  unsigned short* h1s = (unsigned short*)((char*)d_out + (outb - rowb));
  unsigned short* xs = (unsigned short*)((char*)d_out + (outb - 2 * rowb));

  hipMemsetAsync(cnt, 0, (size_t)N * sizeof(int), stream);

  detect_kernel<<<1, 64, 0, stream>>>(edge_raw, flag, E);
  decode_count_kernel<<<(E + 255) / 256, 256, 0, stream>>>(edge_raw, flag, srcA, dstA, rank, cnt, E, N);
  scan1_kernel<<<NB, 256, 0, stream>>>(cnt, rowptr, bsum, N);
  scan2_kernel<<<1, 256, 0, stream>>>(bsum, NB);
  scatter_kernel<<<(E + 255) / 256, 256, 0, stream>>>(srcA, dstA, rank, rowptr, bsum, col, E);
  prep_kernel<<<(N * (CIN / 4) + COUT * CIN / 4 + 255) / 256, 256, 0, stream>>>(x, cnt, xs, W, Wbf, N);

  hop_kernel<true><<<(N + 3) / 4, 256, 0, stream>>>(xs, rowptr, cnt, bsum, col, h1s, N);
  hop_kernel<false><<<(N + 3) / 4, 256, 0, stream>>>(h1s, rowptr, cnt, bsum, col, h2bf, N);

  gemm_kernel<<<(N + 31) / 32, 256, 0, stream>>>(h2bf, Wbf, b, out, N);
}

// Round 4
// 284.255 us; speedup vs baseline: 1.0106x; 1.0106x over previous
//
#include <hip/hip_runtime.h>
#include <hip/hip_bf16.h>

#define CIN 128
#define COUT 512
#define NEG_SLOPE 0.1f

typedef __bf16 bf16x8 __attribute__((ext_vector_type(8)));
typedef float f32x4 __attribute__((ext_vector_type(4)));

static __device__ __forceinline__ unsigned short f2bf(float f) {
  unsigned int u = __builtin_bit_cast(unsigned int, f);
  unsigned int lsb = (u >> 16) & 1u;
  u += 0x7fffu + lsb;  // round-to-nearest-even
  return (unsigned short)(u >> 16);
}
static __device__ __forceinline__ float bf_lo(unsigned int u) {
  return __builtin_bit_cast(float, u << 16);
}
static __device__ __forceinline__ float bf_hi(unsigned int u) {
  return __builtin_bit_cast(float, u & 0xffff0000u);
}
static __device__ __forceinline__ unsigned int pack2(float lo, float hi) {
  return (unsigned int)f2bf(lo) | ((unsigned int)f2bf(hi) << 16);
}

// Fused int64/int32 self-detection + decode + degree count + per-edge rank.
// Detection: in int64 storage every odd int32 word of the src half is 0
// (node ids < 2^31). Each block votes over its own 256 odd words -- safe
// addresses (2e+1 < 2E) in BOTH encodings. P(false int64 on random int32
// data) = P(256 random ids all zero) ~ 0.
__global__ void decode_count_kernel(const int* __restrict__ raw,
                                    int* __restrict__ srcA, int* __restrict__ dstA,
                                    int* __restrict__ rank, int* __restrict__ cnt,
                                    int E, int N) {
  __shared__ int s_is32;
  if (threadIdx.x == 0) s_is32 = 0;
  __syncthreads();
  int e = blockIdx.x * blockDim.x + threadIdx.x;
  int probe = 0;
  if (e < E) probe = raw[2 * e + 1];
  if (probe != 0) s_is32 = 1;  // benign race: any writer writes 1
  __syncthreads();
  if (e >= E) return;
  int s, d;
  if (!s_is32) {  // int64: value in low word of each 8B pair
    int2 sv = ((const int2*)raw)[e];
    int2 dv = ((const int2*)raw)[E + e];
    s = sv.x;
    d = dv.x;
  } else {  // int32 packed
    s = raw[e];
    d = raw[E + e];
  }
  if ((unsigned)s >= (unsigned)N) s = 0;
  if ((unsigned)d >= (unsigned)N) d = 0;
  srcA[e] = s;
  dstA[e] = d;
  rank[e] = atomicAdd(&cnt[d], 1);
}

// Single-pass scan: block-local exclusive scan + block base from a global
// atomic cursor. Segments land in block-ARRIVAL order -- a CSR only needs
// rowptr[i] to point at node i's slice, not monotone rowptr. rowptr is FINAL
// here: no scan2, no bsum folding in consumers.
__global__ __launch_bounds__(256) void scan_kernel(const int* __restrict__ cnt,
                                                   int* __restrict__ rowptr,
                                                   int* __restrict__ gcur, int N) {
  __shared__ int buf[256];
  __shared__ int sbase;
  int tid = threadIdx.x;
  int base = blockIdx.x * 1024 + tid * 4;
  int v[4];
  int tot = 0;
#pragma unroll
  for (int k = 0; k < 4; ++k) {
    int i = base + k;
    v[k] = (i < N) ? cnt[i] : 0;
    tot += v[k];
  }
  buf[tid] = tot;
  __syncthreads();
  for (int off = 1; off < 256; off <<= 1) {
    int t = (tid >= off) ? buf[tid - off] : 0;
    __syncthreads();
    buf[tid] += t;
    __syncthreads();
  }
  if (tid == 255) sbase = atomicAdd(gcur, buf[255]);  // device-scope
  __syncthreads();
  int run = sbase + buf[tid] - tot;
#pragma unroll
  for (int k = 0; k < 4; ++k) {
    int i = base + k;
    if (i < N) rowptr[i] = run;
    run += v[k];
  }
}

// Merged scatter (idx < E) + xscale (idx < N*32) + W->bf16 (next 16384).
// All three are independent and ready once rowptr/cnt exist.
__global__ __launch_bounds__(256) void scatter_prep_kernel(
    const int* __restrict__ srcA, const int* __restrict__ dstA,
    const int* __restrict__ rank, const int* __restrict__ rowptr,
    int* __restrict__ col, int E,
    const float* __restrict__ x, const int* __restrict__ cnt,
    unsigned short* __restrict__ xs,
    const float* __restrict__ W, unsigned short* __restrict__ Wbf, int N) {
  int idx = blockIdx.x * blockDim.x + threadIdx.x;
  if (idx < E) {
    int d = dstA[idx];
    col[rowptr[d] + rank[idx]] = srcA[idx];
  }
  int nx = N * (CIN / 4);
  if (idx < nx) {
    int row = idx >> 5;  // 32 float4 groups per row
    float d = 1.0f / sqrtf((float)(cnt[row] + 1));  // +1 = self-loop
    float4 v = ((const float4*)x)[idx];
    ushort4 o;
    o.x = f2bf(v.x * d); o.y = f2bf(v.y * d); o.z = f2bf(v.z * d); o.w = f2bf(v.w * d);
    ((ushort4*)xs)[idx] = o;
  } else {
    int i = idx - nx;
    if (i < (COUT * CIN / 4)) {
      float4 v = ((const float4*)W)[i];
      ushort4 o;
      o.x = f2bf(v.x); o.y = f2bf(v.y); o.z = f2bf(v.z); o.w = f2bf(v.w);
      ((ushort4*)Wbf)[i] = o;
    }
  }
}

// Gather hop over pre-scaled bf16 rows (256 B/row). One node per wave; grp
// (lane>>4) picks the row, sub (lane&15) the 16B chunk -> wave-uniform trip
// count. Main loop 16 rows/step (4-deep per lane); tail unrolled 8/4/masked
// (<=3 serialized gather rounds, first 2-deep). Cross-grp reduce via shfl_xor.
template <bool SQ>
__global__ __launch_bounds__(256) void hop_kernel(
    const unsigned short* __restrict__ Xs,
    const int* __restrict__ rowptr, const int* __restrict__ cnt,
    const int* __restrict__ col, unsigned short* __restrict__ Y, int N) {
  int lane = threadIdx.x & 63;
  int wid = threadIdx.x >> 6;
  int node = blockIdx.x * 4 + wid;
  if (node >= N) return;
  int sub = lane & 15;
  int grp = lane >> 4;
  int beg = rowptr[node];
  int num = cnt[node];
  const uint4* X4 = (const uint4*)Xs;  // one row = 16 uint4
  float acc[8] = {0.f, 0.f, 0.f, 0.f, 0.f, 0.f, 0.f, 0.f};
  if (grp == 0) {  // self-loop term
    uint4 s = X4[(size_t)node * 16 + sub];
    acc[0] = bf_lo(s.x); acc[1] = bf_hi(s.x);
    acc[2] = bf_lo(s.y); acc[3] = bf_hi(s.y);
    acc[4] = bf_lo(s.z); acc[5] = bf_hi(s.z);
    acc[6] = bf_lo(s.w); acc[7] = bf_hi(s.w);
  }
  const int* cp = col + beg;
  int kb = 0;
  for (; kb + 16 <= num; kb += 16) {
    int j0 = cp[kb + grp];
    int j1 = cp[kb + 4 + grp];
    int j2 = cp[kb + 8 + grp];
    int j3 = cp[kb + 12 + grp];
    uint4 v0 = X4[(size_t)j0 * 16 + sub];
    uint4 v1 = X4[(size_t)j1 * 16 + sub];
    uint4 v2 = X4[(size_t)j2 * 16 + sub];
    uint4 v3 = X4[(size_t)j3 * 16 + sub];
    acc[0] += bf_lo(v0.x); acc[1] += bf_hi(v0.x);
    acc[2] += bf_lo(v0.y); acc[3] += bf_hi(v0.y);
    acc[4] += bf_lo(v0.z); acc[5] += bf_hi(v0.z);
    acc[6] += bf_lo(v0.w); acc[7] += bf_hi(v0.w);
    acc[0] += bf_lo(v1.x); acc[1] += bf_hi(v1.x);
    acc[2] += bf_lo(v1.y); acc[3] += bf_hi(v1.y);
    acc[4] += bf_lo(v1.z); acc[5] += bf_hi(v1.z);
    acc[6] += bf_lo(v1.w); acc[7] += bf_hi(v1.w);
    acc[0] += bf_lo(v2.x); acc[1] += bf_hi(v2.x);
    acc[2] += bf_lo(v2.y); acc[3] += bf_hi(v2.y);
    acc[4] += bf_lo(v2.z); acc[5] += bf_hi(v2.z);
    acc[6] += bf_lo(v2.w); acc[7] += bf_hi(v2.w);
    acc[0] += bf_lo(v3.x); acc[1] += bf_hi(v3.x);
    acc[2] += bf_lo(v3.y); acc[3] += bf_hi(v3.y);
    acc[4] += bf_lo(v3.z); acc[5] += bf_hi(v3.z);
    acc[6] += bf_lo(v3.w); acc[7] += bf_hi(v3.w);
  }
  int rem = num - kb;  // [0,16)
  if (rem >= 8) {      // 2-deep round
    int j0 = cp[kb + grp];
    int j1 = cp[kb + 4 + grp];
    uint4 v0 = X4[(size_t)j0 * 16 + sub];
    uint4 v1 = X4[(size_t)j1 * 16 + sub];
    acc[0] += bf_lo(v0.x); acc[1] += bf_hi(v0.x);
    acc[2] += bf_lo(v0.y); acc[3] += bf_hi(v0.y);
    acc[4] += bf_lo(v0.z); acc[5] += bf_hi(v0.z);
    acc[6] += bf_lo(v0.w); acc[7] += bf_hi(v0.w);
    acc[0] += bf_lo(v1.x); acc[1] += bf_hi(v1.x);
    acc[2] += bf_lo(v1.y); acc[3] += bf_hi(v1.y);
    acc[4] += bf_lo(v1.z); acc[5] += bf_hi(v1.z);
    acc[6] += bf_lo(v1.w); acc[7] += bf_hi(v1.w);
    kb += 8; rem -= 8;
  }
  if (rem >= 4) {
    int j0 = cp[kb + grp];
    uint4 v0 = X4[(size_t)j0 * 16 + sub];
    acc[0] += bf_lo(v0.x); acc[1] += bf_hi(v0.x);
    acc[2] += bf_lo(v0.y); acc[3] += bf_hi(v0.y);
    acc[4] += bf_lo(v0.z); acc[5] += bf_hi(v0.z);
    acc[6] += bf_lo(v0.w); acc[7] += bf_hi(v0.w);
    kb += 4; rem -= 4;
  }
  if (grp < rem) {  // rem in [0,4)
    int j0 = cp[kb + grp];
    uint4 v0 = X4[(size_t)j0 * 16 + sub];
    acc[0] += bf_lo(v0.x); acc[1] += bf_hi(v0.x);
    acc[2] += bf_lo(v0.y); acc[3] += bf_hi(v0.y);
    acc[4] += bf_lo(v0.z); acc[5] += bf_hi(v0.z);
    acc[6] += bf_lo(v0.w); acc[7] += bf_hi(v0.w);
  }
#pragma unroll
  for (int r = 0; r < 8; ++r) acc[r] += __shfl_xor(acc[r], 16, 64);
#pragma unroll
  for (int r = 0; r < 8; ++r) acc[r] += __shfl_xor(acc[r], 32, 64);
  if (grp == 0) {
    float di = 1.0f / sqrtf((float)(num + 1));
    float sc = SQ ? di * di : di;
    uint4 o;
    o.x = pack2(acc[0] * sc, acc[1] * sc);
    o.y = pack2(acc[2] * sc, acc[3] * sc);
    o.z = pack2(acc[4] * sc, acc[5] * sc);
    o.w = pack2(acc[6] * sc, acc[7] * sc);
    ((uint4*)Y)[(size_t)node * 16 + sub] = o;
  }
}

// y = h2 @ W^T + b, LeakyReLU. Block = 32 rows x full COUT=512.
// Swapped-operand MFMA (lane&15 = m, quad*4+reg = n). Epilogue stages each
// 16-row half in LDS then streams it with dense stores (1 KB contiguous per
// wave instruction, full-line HBM writes).
__global__ __launch_bounds__(256) void gemm_kernel(
    const unsigned short* __restrict__ Abf, const unsigned short* __restrict__ Wbf,
    const float* __restrict__ bias, float* __restrict__ out, int M) {
  __shared__ float tile[16 * 516];  // 33 KB
  int wave = threadIdx.x >> 6;
  int lane = threadIdx.x & 63;
  int quad = lane >> 4;
  int l16 = lane & 15;
  int mbase = blockIdx.x * 32;

  int m0 = mbase + l16;
  int m1 = mbase + 16 + l16;
  bool v0 = m0 < M;
  bool v1 = m1 < M;

  bf16x8 af[2][4];
#pragma unroll
  for (int kk = 0; kk < 4; ++kk) {
    af[0][kk] = v0 ? *(const bf16x8*)(Abf + (size_t)m0 * CIN + kk * 32 + quad * 8) : bf16x8{};
    af[1][kk] = v1 ? *(const bf16x8*)(Abf + (size_t)m1 * CIN + kk * 32 + quad * 8) : bf16x8{};
  }

  int nbase = wave * 128;
  f32x4 acc0[8], acc1[8];
#pragma unroll
  for (int nt = 0; nt < 8; ++nt) {
    int nrow = nbase + nt * 16 + l16;  // W row this lane loads (A-operand)
    bf16x8 wf[4];
#pragma unroll
    for (int kk = 0; kk < 4; ++kk)
      wf[kk] = *(const bf16x8*)(Wbf + (size_t)nrow * CIN + kk * 32 + quad * 8);
    f32x4 a0 = {}, a1 = {};
#pragma unroll
    for (int kk = 0; kk < 4; ++kk) {
      a0 = __builtin_amdgcn_mfma_f32_16x16x32_bf16(wf[kk], af[0][kk], a0, 0, 0, 0);
      a1 = __builtin_amdgcn_mfma_f32_16x16x32_bf16(wf[kk], af[1][kk], a1, 0, 0, 0);
    }
    acc0[nt] = a0;
    acc1[nt] = a1;
  }

#pragma unroll
  for (int half = 0; half < 2; ++half) {
    if (half) __syncthreads();  // WAR: previous half streamed out
#pragma unroll
    for (int nt = 0; nt < 8; ++nt) {
      int n0 = nbase + nt * 16 + quad * 4;
      float4 bv = *(const float4*)(bias + n0);
      f32x4 a = half ? acc1[nt] : acc0[nt];
      float4 o;
      o.x = a[0] + bv.x; o.x = (o.x >= 0.f) ? o.x : NEG_SLOPE * o.x;
      o.y = a[1] + bv.y; o.y = (o.y >= 0.f) ? o.y : NEG_SLOPE * o.y;
      o.z = a[2] + bv.z; o.z = (o.z >= 0.f) ? o.z : NEG_SLOPE * o.z;
      o.w = a[3] + bv.w; o.w = (o.w >= 0.f) ? o.w : NEG_SLOPE * o.w;
      *(float4*)&tile[l16 * 516 + n0] = o;
    }
    __syncthreads();
#pragma unroll
    for (int it = 0; it < 8; ++it) {
      int r = it * 2 + (threadIdx.x >> 7);
      int c = (threadIdx.x & 127) * 4;
      int m = mbase + half * 16 + r;
      if (m < M) *(float4*)(out + (size_t)m * COUT + c) = *(const float4*)&tile[r * 516 + c];
    }
  }
}

static inline size_t align_up(size_t v, size_t a) { return (v + a - 1) & ~(a - 1); }

extern "C" void kernel_launch(void* const* d_in, const int* in_sizes, int n_in,
                              void* d_out, int out_size, void* d_ws, size_t ws_size,
                              hipStream_t stream) {
  const float* x = (const float*)d_in[0];
  const int* edge_raw = (const int*)d_in[1];
  const float* W = (const float*)d_in[2];
  const float* b = (const float*)d_in[3];
  float* out = (float*)d_out;

  const int N = in_sizes[0] / CIN;
  const int E = in_sizes[1] / 2;
  const int NB = (N + 1023) / 1024;  // scan blocks (49 for N=50000)

  // Workspace layout. gcur sits directly before cnt so ONE memset zeroes both.
  char* w = (char*)d_ws;
  int* gcur = (int*)w;            w += 256;
  int* cnt = (int*)w;             w += align_up((size_t)N * 4, 256);
  int* rowptr = (int*)w;          w += align_up((size_t)N * 4, 256);
  int* srcA = (int*)w;            w += align_up((size_t)E * 4, 256);
  int* dstA = (int*)w;            w += align_up((size_t)E * 4, 256);
  int* rank = (int*)w;            w += align_up((size_t)E * 4, 256);
  int* col = (int*)w;             w += align_up((size_t)E * 4, 256);
  unsigned short* h2bf = (unsigned short*)w;  w += align_up((size_t)N * CIN * 2, 256);
  unsigned short* Wbf = (unsigned short*)w;   w += align_up((size_t)COUT * CIN * 2, 256);

  // bf16 row buffers in the tail of d_out (scratch until GEMM's final write).
  size_t outb = (size_t)out_size * sizeof(float);
  size_t rowb = (size_t)N * CIN * sizeof(unsigned short);
  unsigned short* h1s = (unsigned short*)((char*)d_out + (outb - rowb));
  unsigned short* xs = (unsigned short*)((char*)d_out + (outb - 2 * rowb));

  hipMemsetAsync(gcur, 0, 256 + (size_t)N * sizeof(int), stream);

  decode_count_kernel<<<(E + 255) / 256, 256, 0, stream>>>(edge_raw, srcA, dstA, rank, cnt, E, N);
  scan_kernel<<<NB, 256, 0, stream>>>(cnt, rowptr, gcur, N);

  int prep_elems = N * (CIN / 4) + COUT * CIN / 4;
  int sp_threads = (E > prep_elems) ? E : prep_elems;
  scatter_prep_kernel<<<(sp_threads + 255) / 256, 256, 0, stream>>>(
      srcA, dstA, rank, rowptr, col, E, x, cnt, xs, W, Wbf, N);

  hop_kernel<true><<<(N + 3) / 4, 256, 0, stream>>>(xs, rowptr, cnt, col, h1s, N);
  hop_kernel<false><<<(N + 3) / 4, 256, 0, stream>>>(h1s, rowptr, cnt, col, h2bf, N);

  gemm_kernel<<<(N + 31) / 32, 256, 0, stream>>>(h2bf, Wbf, b, out, N);
}

// Round 5
// 266.050 us; speedup vs baseline: 1.0798x; 1.0684x over previous
//
#include <hip/hip_runtime.h>
#include <hip/hip_bf16.h>

#define CIN 128
#define COUT 512
#define NEG_SLOPE 0.1f

typedef __bf16 bf16x8 __attribute__((ext_vector_type(8)));
typedef float f32x4 __attribute__((ext_vector_type(4)));

static __device__ __forceinline__ unsigned short f2bf(float f) {
  unsigned int u = __builtin_bit_cast(unsigned int, f);
  unsigned int lsb = (u >> 16) & 1u;
  u += 0x7fffu + lsb;  // round-to-nearest-even
  return (unsigned short)(u >> 16);
}
static __device__ __forceinline__ float bf_lo(unsigned int u) {
  return __builtin_bit_cast(float, u << 16);
}
static __device__ __forceinline__ float bf_hi(unsigned int u) {
  return __builtin_bit_cast(float, u & 0xffff0000u);
}
static __device__ __forceinline__ unsigned int pack2(float lo, float hi) {
  return (unsigned int)f2bf(lo) | ((unsigned int)f2bf(hi) << 16);
}

// Fused int64/int32 self-detection + decode + degree count + per-edge rank.
// Detection: in int64 storage every odd int32 word of the src half is 0
// (node ids < 2^31). Each block votes over its own 256 odd words -- safe
// addresses (2e+1 < 2E) in BOTH encodings. P(false int64 on random int32
// data) = P(256 random ids all zero) ~ 0.
__global__ void decode_count_kernel(const int* __restrict__ raw,
                                    int* __restrict__ srcA, int* __restrict__ dstA,
                                    int* __restrict__ rank, int* __restrict__ cnt,
                                    int E, int N) {
  __shared__ int s_is32;
  if (threadIdx.x == 0) s_is32 = 0;
  __syncthreads();
  int e = blockIdx.x * blockDim.x + threadIdx.x;
  int probe = 0;
  if (e < E) probe = raw[2 * e + 1];
  if (probe != 0) s_is32 = 1;  // benign race: any writer writes 1
  __syncthreads();
  if (e >= E) return;
  int s, d;
  if (!s_is32) {  // int64: value in low word of each 8B pair
    int2 sv = ((const int2*)raw)[e];
    int2 dv = ((const int2*)raw)[E + e];
    s = sv.x;
    d = dv.x;
  } else {  // int32 packed
    s = raw[e];
    d = raw[E + e];
  }
  if ((unsigned)s >= (unsigned)N) s = 0;
  if ((unsigned)d >= (unsigned)N) d = 0;
  srcA[e] = s;
  dstA[e] = d;
  rank[e] = atomicAdd(&cnt[d], 1);
}

// Single-pass scan: block-local exclusive scan + block base from a global
// atomic cursor. Segments land in block-ARRIVAL order -- a CSR only needs
// rowptr[i] to point at node i's slice, not monotone rowptr.
__global__ __launch_bounds__(256) void scan_kernel(const int* __restrict__ cnt,
                                                   int* __restrict__ rowptr,
                                                   int* __restrict__ gcur, int N) {
  __shared__ int buf[256];
  __shared__ int sbase;
  int tid = threadIdx.x;
  int base = blockIdx.x * 1024 + tid * 4;
  int v[4];
  int tot = 0;
#pragma unroll
  for (int k = 0; k < 4; ++k) {
    int i = base + k;
    v[k] = (i < N) ? cnt[i] : 0;
    tot += v[k];
  }
  buf[tid] = tot;
  __syncthreads();
  for (int off = 1; off < 256; off <<= 1) {
    int t = (tid >= off) ? buf[tid - off] : 0;
    __syncthreads();
    buf[tid] += t;
    __syncthreads();
  }
  if (tid == 255) sbase = atomicAdd(gcur, buf[255]);  // device-scope
  __syncthreads();
  int run = sbase + buf[tid] - tot;
#pragma unroll
  for (int k = 0; k < 4; ++k) {
    int i = base + k;
    if (i < N) rowptr[i] = run;
    run += v[k];
  }
}

// Merged scatter (idx < E) + xscale (idx < N*32) + W->bf16 MFMA-FRAGMENT
// SHUFFLE (next 8192 16B-groups).
// Wshuf layout: fragment element j of (wave, nt, kk, lane) lives at
//   Wshuf[(((wave*8+nt)*4+kk)*64 + lane)*8 + j]
// so each gemm wf load is 64 lanes x 16 B CONTIGUOUS (1 KB/instr, zero
// line overfetch). The old row-major layout made every wf load touch 64
// distinct 256B-strided lines -> 4x L2 overfetch, ~820 MB of L2 reads.
__global__ __launch_bounds__(256) void scatter_prep_kernel(
    const int* __restrict__ srcA, const int* __restrict__ dstA,
    const int* __restrict__ rank, const int* __restrict__ rowptr,
    int* __restrict__ col, int E,
    const float* __restrict__ x, const int* __restrict__ cnt,
    unsigned short* __restrict__ xs,
    const float* __restrict__ W, unsigned short* __restrict__ Wbf, int N) {
  int idx = blockIdx.x * blockDim.x + threadIdx.x;
  if (idx < E) {
    int d = dstA[idx];
    col[rowptr[d] + rank[idx]] = srcA[idx];
  }
  int nx = N * (CIN / 4);
  if (idx < nx) {
    int row = idx >> 5;  // 32 float4 groups per row
    float d = 1.0f / sqrtf((float)(cnt[row] + 1));  // +1 = self-loop
    float4 v = ((const float4*)x)[idx];
    ushort4 o;
    o.x = f2bf(v.x * d); o.y = f2bf(v.y * d); o.z = f2bf(v.z * d); o.w = f2bf(v.w * d);
    ((ushort4*)xs)[idx] = o;
  } else {
    int t = idx - nx;  // one 16B fragment (8 bf16) of Wshuf
    if (t < (COUT * CIN / 8)) {
      int lane = t & 63;
      int kk = (t >> 6) & 3;
      int nt = (t >> 8) & 7;
      int wv = t >> 11;  // 0..3
      int row = wv * 128 + nt * 16 + (lane & 15);
      int c = kk * 32 + (lane >> 4) * 8;
      const float* src = W + (size_t)row * CIN + c;
      float4 v0 = *(const float4*)src;
      float4 v1 = *(const float4*)(src + 4);
      ushort4 o0, o1;
      o0.x = f2bf(v0.x); o0.y = f2bf(v0.y); o0.z = f2bf(v0.z); o0.w = f2bf(v0.w);
      o1.x = f2bf(v1.x); o1.y = f2bf(v1.y); o1.z = f2bf(v1.z); o1.w = f2bf(v1.w);
      ((ushort4*)Wbf)[2 * t] = o0;
      ((ushort4*)Wbf)[2 * t + 1] = o1;
    }
  }
}

// Gather hop over pre-scaled bf16 rows (256 B/row). One node per wave; grp
// (lane>>4) picks the row, sub (lane&15) the 16B chunk -> wave-uniform trip
// count. Main loop 16 rows/step (4-deep per lane); tail unrolled 8/4/masked.
template <bool SQ>
__global__ __launch_bounds__(256) void hop_kernel(
    const unsigned short* __restrict__ Xs,
    const int* __restrict__ rowptr, const int* __restrict__ cnt,
    const int* __restrict__ col, unsigned short* __restrict__ Y, int N) {
  int lane = threadIdx.x & 63;
  int wid = threadIdx.x >> 6;
  int node = blockIdx.x * 4 + wid;
  if (node >= N) return;
  int sub = lane & 15;
  int grp = lane >> 4;
  int beg = rowptr[node];
  int num = cnt[node];
  const uint4* X4 = (const uint4*)Xs;  // one row = 16 uint4
  float acc[8] = {0.f, 0.f, 0.f, 0.f, 0.f, 0.f, 0.f, 0.f};
  if (grp == 0) {  // self-loop term
    uint4 s = X4[(size_t)node * 16 + sub];
    acc[0] = bf_lo(s.x); acc[1] = bf_hi(s.x);
    acc[2] = bf_lo(s.y); acc[3] = bf_hi(s.y);
    acc[4] = bf_lo(s.z); acc[5] = bf_hi(s.z);
    acc[6] = bf_lo(s.w); acc[7] = bf_hi(s.w);
  }
  const int* cp = col + beg;
  int kb = 0;
  for (; kb + 16 <= num; kb += 16) {
    int j0 = cp[kb + grp];
    int j1 = cp[kb + 4 + grp];
    int j2 = cp[kb + 8 + grp];
    int j3 = cp[kb + 12 + grp];
    uint4 v0 = X4[(size_t)j0 * 16 + sub];
    uint4 v1 = X4[(size_t)j1 * 16 + sub];
    uint4 v2 = X4[(size_t)j2 * 16 + sub];
    uint4 v3 = X4[(size_t)j3 * 16 + sub];
    acc[0] += bf_lo(v0.x); acc[1] += bf_hi(v0.x);
    acc[2] += bf_lo(v0.y); acc[3] += bf_hi(v0.y);
    acc[4] += bf_lo(v0.z); acc[5] += bf_hi(v0.z);
    acc[6] += bf_lo(v0.w); acc[7] += bf_hi(v0.w);
    acc[0] += bf_lo(v1.x); acc[1] += bf_hi(v1.x);
    acc[2] += bf_lo(v1.y); acc[3] += bf_hi(v1.y);
    acc[4] += bf_lo(v1.z); acc[5] += bf_hi(v1.z);
    acc[6] += bf_lo(v1.w); acc[7] += bf_hi(v1.w);
    acc[0] += bf_lo(v2.x); acc[1] += bf_hi(v2.x);
    acc[2] += bf_lo(v2.y); acc[3] += bf_hi(v2.y);
    acc[4] += bf_lo(v2.z); acc[5] += bf_hi(v2.z);
    acc[6] += bf_lo(v2.w); acc[7] += bf_hi(v2.w);
    acc[0] += bf_lo(v3.x); acc[1] += bf_hi(v3.x);
    acc[2] += bf_lo(v3.y); acc[3] += bf_hi(v3.y);
    acc[4] += bf_lo(v3.z); acc[5] += bf_hi(v3.z);
    acc[6] += bf_lo(v3.w); acc[7] += bf_hi(v3.w);
  }
  int rem = num - kb;  // [0,16)
  if (rem >= 8) {      // 2-deep round
    int j0 = cp[kb + grp];
    int j1 = cp[kb + 4 + grp];
    uint4 v0 = X4[(size_t)j0 * 16 + sub];
    uint4 v1 = X4[(size_t)j1 * 16 + sub];
    acc[0] += bf_lo(v0.x); acc[1] += bf_hi(v0.x);
    acc[2] += bf_lo(v0.y); acc[3] += bf_hi(v0.y);
    acc[4] += bf_lo(v0.z); acc[5] += bf_hi(v0.z);
    acc[6] += bf_lo(v0.w); acc[7] += bf_hi(v0.w);
    acc[0] += bf_lo(v1.x); acc[1] += bf_hi(v1.x);
    acc[2] += bf_lo(v1.y); acc[3] += bf_hi(v1.y);
    acc[4] += bf_lo(v1.z); acc[5] += bf_hi(v1.z);
    acc[6] += bf_lo(v1.w); acc[7] += bf_hi(v1.w);
    kb += 8; rem -= 8;
  }
  if (rem >= 4) {
    int j0 = cp[kb + grp];
    uint4 v0 = X4[(size_t)j0 * 16 + sub];
    acc[0] += bf_lo(v0.x); acc[1] += bf_hi(v0.x);
    acc[2] += bf_lo(v0.y); acc[3] += bf_hi(v0.y);
    acc[4] += bf_lo(v0.z); acc[5] += bf_hi(v0.z);
    acc[6] += bf_lo(v0.w); acc[7] += bf_hi(v0.w);
    kb += 4; rem -= 4;
  }
  if (grp < rem) {  // rem in [0,4)
    int j0 = cp[kb + grp];
    uint4 v0 = X4[(size_t)j0 * 16 + sub];
    acc[0] += bf_lo(v0.x); acc[1] += bf_hi(v0.x);
    acc[2] += bf_lo(v0.y); acc[3] += bf_hi(v0.y);
    acc[4] += bf_lo(v0.z); acc[5] += bf_hi(v0.z);
    acc[6] += bf_lo(v0.w); acc[7] += bf_hi(v0.w);
  }
#pragma unroll
  for (int r = 0; r < 8; ++r) acc[r] += __shfl_xor(acc[r], 16, 64);
#pragma unroll
  for (int r = 0; r < 8; ++r) acc[r] += __shfl_xor(acc[r], 32, 64);
  if (grp == 0) {
    float di = 1.0f / sqrtf((float)(num + 1));
    float sc = SQ ? di * di : di;
    uint4 o;
    o.x = pack2(acc[0] * sc, acc[1] * sc);
    o.y = pack2(acc[2] * sc, acc[3] * sc);
    o.z = pack2(acc[4] * sc, acc[5] * sc);
    o.w = pack2(acc[6] * sc, acc[7] * sc);
    ((uint4*)Y)[(size_t)node * 16 + sub] = o;
  }
}

// y = h2 @ W^T + b, LeakyReLU. Block = 32 rows x full COUT=512.
// Swapped-operand MFMA (lane&15 = m, quad*4+reg = n). W is pre-shuffled into
// fragment order (see scatter_prep_kernel) so every wf load is one 1 KB
// contiguous wave load -- the block streams W exactly once with no overfetch.
// Epilogue stages each 16-row half in LDS, then dense 1 KB/instr stores.
__global__ __launch_bounds__(256) void gemm_kernel(
    const unsigned short* __restrict__ Abf, const unsigned short* __restrict__ Wbf,
    const float* __restrict__ bias, float* __restrict__ out, int M) {
  __shared__ float tile[16 * 516];  // 33 KB
  int wave = threadIdx.x >> 6;
  int lane = threadIdx.x & 63;
  int quad = lane >> 4;
  int l16 = lane & 15;
  int mbase = blockIdx.x * 32;

  int m0 = mbase + l16;
  int m1 = mbase + 16 + l16;
  bool v0 = m0 < M;
  bool v1 = m1 < M;

  bf16x8 af[2][4];
#pragma unroll
  for (int kk = 0; kk < 4; ++kk) {
    af[0][kk] = v0 ? *(const bf16x8*)(Abf + (size_t)m0 * CIN + kk * 32 + quad * 8) : bf16x8{};
    af[1][kk] = v1 ? *(const bf16x8*)(Abf + (size_t)m1 * CIN + kk * 32 + quad * 8) : bf16x8{};
  }

  const bf16x8* Wf = (const bf16x8*)Wbf;  // fragment-ordered
  int nbase = wave * 128;
  f32x4 acc0[8], acc1[8];
#pragma unroll
  for (int nt = 0; nt < 8; ++nt) {
    bf16x8 wf[4];
#pragma unroll
    for (int kk = 0; kk < 4; ++kk)
      wf[kk] = Wf[(((wave * 8 + nt) * 4 + kk) << 6) + lane];
    f32x4 a0 = {}, a1 = {};
#pragma unroll
    for (int kk = 0; kk < 4; ++kk) {
      a0 = __builtin_amdgcn_mfma_f32_16x16x32_bf16(wf[kk], af[0][kk], a0, 0, 0, 0);
      a1 = __builtin_amdgcn_mfma_f32_16x16x32_bf16(wf[kk], af[1][kk], a1, 0, 0, 0);
    }
    acc0[nt] = a0;
    acc1[nt] = a1;
  }

#pragma unroll
  for (int half = 0; half < 2; ++half) {
    if (half) __syncthreads();  // WAR: previous half streamed out
#pragma unroll
    for (int nt = 0; nt < 8; ++nt) {
      int n0 = nbase + nt * 16 + quad * 4;
      float4 bv = *(const float4*)(bias + n0);
      f32x4 a = half ? acc1[nt] : acc0[nt];
      float4 o;
      o.x = a[0] + bv.x; o.x = (o.x >= 0.f) ? o.x : NEG_SLOPE * o.x;
      o.y = a[1] + bv.y; o.y = (o.y >= 0.f) ? o.y : NEG_SLOPE * o.y;
      o.z = a[2] + bv.z; o.z = (o.z >= 0.f) ? o.z : NEG_SLOPE * o.z;
      o.w = a[3] + bv.w; o.w = (o.w >= 0.f) ? o.w : NEG_SLOPE * o.w;
      *(float4*)&tile[l16 * 516 + n0] = o;
    }
    __syncthreads();
#pragma unroll
    for (int it = 0; it < 8; ++it) {
      int r = it * 2 + (threadIdx.x >> 7);
      int c = (threadIdx.x & 127) * 4;
      int m = mbase + half * 16 + r;
      if (m < M) *(float4*)(out + (size_t)m * COUT + c) = *(const float4*)&tile[r * 516 + c];
    }
  }
}

static inline size_t align_up(size_t v, size_t a) { return (v + a - 1) & ~(a - 1); }

extern "C" void kernel_launch(void* const* d_in, const int* in_sizes, int n_in,
                              void* d_out, int out_size, void* d_ws, size_t ws_size,
                              hipStream_t stream) {
  const float* x = (const float*)d_in[0];
  const int* edge_raw = (const int*)d_in[1];
  const float* W = (const float*)d_in[2];
  const float* b = (const float*)d_in[3];
  float* out = (float*)d_out;

  const int N = in_sizes[0] / CIN;
  const int E = in_sizes[1] / 2;
  const int NB = (N + 1023) / 1024;  // scan blocks (49 for N=50000)

  // Workspace layout. gcur sits directly before cnt so ONE memset zeroes both.
  char* w = (char*)d_ws;
  int* gcur = (int*)w;            w += 256;
  int* cnt = (int*)w;             w += align_up((size_t)N * 4, 256);
  int* rowptr = (int*)w;          w += align_up((size_t)N * 4, 256);
  int* srcA = (int*)w;            w += align_up((size_t)E * 4, 256);
  int* dstA = (int*)w;            w += align_up((size_t)E * 4, 256);
  int* rank = (int*)w;            w += align_up((size_t)E * 4, 256);
  int* col = (int*)w;             w += align_up((size_t)E * 4, 256);
  unsigned short* h2bf = (unsigned short*)w;  w += align_up((size_t)N * CIN * 2, 256);
  unsigned short* Wbf = (unsigned short*)w;   w += align_up((size_t)COUT * CIN * 2, 256);

  // bf16 row buffers in the tail of d_out (scratch until GEMM's final write).
  size_t outb = (size_t)out_size * sizeof(float);
  size_t rowb = (size_t)N * CIN * sizeof(unsigned short);
  unsigned short* h1s = (unsigned short*)((char*)d_out + (outb - rowb));
  unsigned short* xs = (unsigned short*)((char*)d_out + (outb - 2 * rowb));

  hipMemsetAsync(gcur, 0, 256 + (size_t)N * sizeof(int), stream);

  decode_count_kernel<<<(E + 255) / 256, 256, 0, stream>>>(edge_raw, srcA, dstA, rank, cnt, E, N);
  scan_kernel<<<NB, 256, 0, stream>>>(cnt, rowptr, gcur, N);

  int prep_elems = N * (CIN / 4) + COUT * CIN / 8;
  int sp_threads = (E > prep_elems) ? E : prep_elems;
  scatter_prep_kernel<<<(sp_threads + 255) / 256, 256, 0, stream>>>(
      srcA, dstA, rank, rowptr, col, E, x, cnt, xs, W, Wbf, N);

  hop_kernel<true><<<(N + 3) / 4, 256, 0, stream>>>(xs, rowptr, cnt, col, h1s, N);
  hop_kernel<false><<<(N + 3) / 4, 256, 0, stream>>>(h1s, rowptr, cnt, col, h2bf, N);

  gemm_kernel<<<(N + 31) / 32, 256, 0, stream>>>(h2bf, Wbf, b, out, N);
}